// Round 2
// baseline (1043.820 us; speedup 1.0000x reference)
//
#include <hip/hip_runtime.h>
#include <stdint.h>

// ---------------- types & helpers ----------------
typedef __attribute__((ext_vector_type(8))) short short8;
typedef __attribute__((ext_vector_type(4))) short short4v;
typedef __attribute__((ext_vector_type(4))) float f32x4;

#define GLOAD16(gp, lp) __builtin_amdgcn_global_load_lds( \
    (__attribute__((address_space(1))) void*)(gp),        \
    (__attribute__((address_space(3))) void*)(lp), 16, 0, 0)

#define BAR   __builtin_amdgcn_s_barrier()
#define LGKM0 asm volatile("s_waitcnt lgkmcnt(0)" ::: "memory")
#define VMCNT4 asm volatile("s_waitcnt vmcnt(4)" ::: "memory")

__device__ __forceinline__ unsigned short f2bf(float f) {
    union { float f; unsigned u; } v; v.f = f;
    unsigned u = v.u + 0x7fffu + ((v.u >> 16) & 1u);
    return (unsigned short)(u >> 16);
}
__device__ __forceinline__ float bf2f(short s) {
    union { unsigned u; float f; } v;
    v.u = ((unsigned)(unsigned short)s) << 16;
    return v.f;
}

// ---------------- fp32 -> bf16 convert ----------------
__global__ __launch_bounds__(256) void cvt_f32_bf16(const float* __restrict__ in,
                                                    short* __restrict__ out) {
    const int i = (blockIdx.x * 256 + threadIdx.x) * 4;
    const float4 v = *(const float4*)(in + i);
    short4v o;
    o[0] = (short)f2bf(v.x); o[1] = (short)f2bf(v.y);
    o[2] = (short)f2bf(v.z); o[3] = (short)f2bf(v.w);
    *(short4v*)(out + i) = o;
}

// ---------------- fp32 [R][C] -> bf16 [C][R] transpose+convert ----------------
__global__ __launch_bounds__(256) void transpose_cvt(const float* __restrict__ in,
                                                     short* __restrict__ out,
                                                     int R, int C) {
    __shared__ float tile[64 * 65];
    const int t = threadIdx.x;
    const int r0 = blockIdx.y * 64, c0 = blockIdx.x * 64;
    const int rl = t >> 4, cl4 = (t & 15) * 4;
#pragma unroll
    for (int rep = 0; rep < 4; rep++) {
        const int r = rep * 16 + rl;
        const float4 v = *(const float4*)(in + (long)(r0 + r) * C + c0 + cl4);
        tile[r * 65 + cl4 + 0] = v.x;
        tile[r * 65 + cl4 + 1] = v.y;
        tile[r * 65 + cl4 + 2] = v.z;
        tile[r * 65 + cl4 + 3] = v.w;
    }
    __syncthreads();
#pragma unroll
    for (int rep = 0; rep < 4; rep++) {
        const int cc = rep * 16 + rl;
        short4v o;
#pragma unroll
        for (int j = 0; j < 4; j++) o[j] = (short)f2bf(tile[(cl4 + j) * 65 + cc]);
        *(short4v*)(out + (long)(c0 + cc) * R + r0 + cl4) = o;
    }
}

// ---------------- bf16 V transpose ----------------
__global__ __launch_bounds__(256) void vtrans(const short* __restrict__ QKV,
                                              short* __restrict__ Vt) {
    __shared__ short tile[64 * 72];
    const int t = threadIdx.x;
    const int s0 = blockIdx.x * 64, d0 = blockIdx.y * 64;
    const int hb = blockIdx.z >> 1, b = blockIdx.z & 1;
    const short* src = QKV + ((long)(24 + hb) * 4096 + b * 2048) * 256;
    short* dst = Vt + (long)blockIdx.z * 256 * 2048;
#pragma unroll
    for (int p = 0; p < 2; p++) {
        const int c = p * 256 + t;
        const int r = c >> 3, col8 = (c & 7) * 8;
        *(short8*)(tile + r * 72 + col8) = *(const short8*)(src + (long)(s0 + r) * 256 + d0 + col8);
    }
    __syncthreads();
#pragma unroll
    for (int p = 0; p < 2; p++) {
        const int c = p * 256 + t;
        const int dr = c >> 3, sc8 = (c & 7) * 8;
        short8 o;
#pragma unroll
        for (int j = 0; j < 8; j++) o[j] = tile[(sc8 + j) * 72 + dr];
        *(short8*)(dst + (long)(d0 + dr) * 2048 + s0 + sc8) = o;
    }
}

// ---------------- NT GEMM (128x128 m97-structure; kept for o-proj) ----------------
template<int N, int K, int OUTMODE>
__global__ __launch_bounds__(256) void gemm_nt(const short* __restrict__ A,
                                               const short* __restrict__ Bt,
                                               void* __restrict__ Cv) {
    __shared__ __align__(16) short Al[128 * 32];
    __shared__ __align__(16) short Bl[128 * 32];
    const int t = threadIdx.x;
    const int lane = t & 63, w = t >> 6;
    const int quad = lane >> 4, l16 = lane & 15;
    const int wr = w >> 1, wc = w & 1;
    const long m0 = (long)blockIdx.y * 128, n0 = (long)blockIdx.x * 128;

    const short* Ag0 = A + (m0 + (t >> 2)) * K + (t & 3) * 8;
    const short* Bg0 = Bt + (n0 + (t >> 2)) * K + (t & 3) * 8;

    f32x4 acc[4][4] = {};

    for (int k0 = 0; k0 < K; k0 += 32) {
        __syncthreads();
        GLOAD16(Ag0 + k0,            Al + t * 8);
        GLOAD16(Ag0 + 64 * K + k0,   Al + (t + 256) * 8);
        GLOAD16(Bg0 + k0,            Bl + t * 8);
        GLOAD16(Bg0 + 64 * K + k0,   Bl + (t + 256) * 8);
        __syncthreads();
        short8 af[4], bfr[4];
#pragma unroll
        for (int i = 0; i < 4; i++)
            af[i] = *(const short8*)(Al + (wr * 64 + i * 16 + l16) * 32 + quad * 8);
#pragma unroll
        for (int i = 0; i < 4; i++)
            bfr[i] = *(const short8*)(Bl + (wc * 64 + i * 16 + l16) * 32 + quad * 8);
#pragma unroll
        for (int mi = 0; mi < 4; mi++)
#pragma unroll
            for (int ni = 0; ni < 4; ni++)
                acc[mi][ni] = __builtin_amdgcn_mfma_f32_16x16x32_bf16(af[mi], bfr[ni], acc[mi][ni], 0, 0, 0);
    }

    const long crow = m0 + wr * 64 + quad * 4;
    const long ccol = n0 + wc * 64 + l16;
    if constexpr (OUTMODE == 0) {
        float* C = (float*)Cv;
#pragma unroll
        for (int mi = 0; mi < 4; mi++)
#pragma unroll
            for (int ni = 0; ni < 4; ni++)
#pragma unroll
                for (int r = 0; r < 4; r++)
                    C[(crow + mi * 16 + r) * N + ccol + ni * 16] = acc[mi][ni][r];
    } else {
        short* C = (short*)Cv;
#pragma unroll
        for (int mi = 0; mi < 4; mi++)
#pragma unroll
            for (int ni = 0; ni < 4; ni++)
#pragma unroll
                for (int r = 0; r < 4; r++) {
                    const long m = crow + mi * 16 + r;
                    const long f = ccol + ni * 16;
                    C[(f >> 8) * 1048576 + m * 256 + (f & 255)] = (short)f2bf(acc[mi][ni][r]);
                }
    }
}

// ---------------- 256x256 8-phase NT GEMM -> QKV scatter (T1+T2+T3/T4+T5) ----------------
__global__ __launch_bounds__(512, 2) void gemm256_qkv(const short* __restrict__ A,
                                                      const short* __restrict__ Bt,
                                                      short* __restrict__ QKV) {
    constexpr int K = 2048;
    constexpr int NTM = 31;                       // (K/64) - 1, pow2 wrap for tail stages
    __shared__ __align__(16) short L[2][4][8192]; // [buf][A0,A1,B0,B1][128*64]

    const int t = threadIdx.x;
    const int lane = t & 63, w = t >> 6;
    const int quad = lane >> 4, l16 = lane & 15;
    const int wr = w >> 2, wc = w & 3;
    const int bh = 2 + (wc >> 1);        // this wave's B half-slot
    const int brow0 = (wc & 1) * 64;     // B in-half row base

    // T1: bijective XCD swizzle (nwg = 512, 512 % 8 == 0)
    const int flat = blockIdx.y * 32 + blockIdx.x;
    const int swz = (flat & 7) * 64 + (flat >> 3);
    const int bx = swz & 31, by = swz >> 5;
    const long m0 = (long)by * 256, n0 = (long)bx * 256;

    // staging sources: linear LDS dest, inverse-st_16x32 pre-swizzled global k
    const int r0 = t >> 3, r1 = (512 + t) >> 3;
    const int k0s = ((t & 7) * 8) ^ (((r0 >> 2) & 1) << 4);
    const int k1s = ((t & 7) * 8) ^ (((r1 >> 2) & 1) << 4);
    const short* aS0 = A + (m0 + r0) * K + k0s;
    const short* aS1 = A + (m0 + r1) * K + k1s;
    const short* aT0 = aS0 + 128 * K;
    const short* aT1 = aS1 + 128 * K;
    const short* bS0 = Bt + (n0 + r0) * K + k0s;
    const short* bS1 = Bt + (n0 + r1) * K + k1s;
    const short* bT0 = bS0 + 128 * K;
    const short* bT1 = bS1 + 128 * K;

#define STG(p0, p1, bsel, slot, kt) do {                     \
    const int _ko = ((kt) & NTM) * 64;                       \
    GLOAD16((p0) + _ko, &L[bsel][slot][t * 8]);              \
    GLOAD16((p1) + _ko, &L[bsel][slot][4096 + t * 8]);       \
} while (0)

#define LDA4(bsel, rb) do {                                                        \
    _Pragma("unroll") for (int m = 0; m < 4; ++m) {                                \
        const int _r = (rb) + m * 16 + l16;                                        \
        const int _sw = ((_r >> 2) & 1) << 4;                                      \
        a[m][0] = *(const short8*)(&L[bsel][wr][_r * 64 + ((quad * 8) ^ _sw)]);    \
        a[m][1] = *(const short8*)(&L[bsel][wr][_r * 64 + ((32 + quad * 8) ^ _sw)]); \
    } } while (0)

#define LDB2(bsel, nb) do {                                                        \
    _Pragma("unroll") for (int n = 0; n < 2; ++n) {                                \
        const int _r = brow0 + ((nb) + n) * 16 + l16;                              \
        const int _sw = ((_r >> 2) & 1) << 4;                                      \
        b[(nb) + n][0] = *(const short8*)(&L[bsel][bh][_r * 64 + ((quad * 8) ^ _sw)]); \
        b[(nb) + n][1] = *(const short8*)(&L[bsel][bh][_r * 64 + ((32 + quad * 8) ^ _sw)]); \
    } } while (0)

#define PH_MFMA(MB, NB)                                                            \
    __builtin_amdgcn_s_setprio(1);                                                 \
    _Pragma("unroll") for (int m = 0; m < 4; ++m)                                  \
    _Pragma("unroll") for (int n = 0; n < 2; ++n)                                  \
    _Pragma("unroll") for (int kk = 0; kk < 2; ++kk)                               \
        acc[(MB) + m][(NB) + n] = __builtin_amdgcn_mfma_f32_16x16x32_bf16(         \
            a[m][kk], b[(NB) + n][kk], acc[(MB) + m][(NB) + n], 0, 0, 0);          \
    __builtin_amdgcn_s_setprio(0);

    short8 a[4][2], b[4][2];
    f32x4 acc[8][4] = {};

    STG(aS0, aS1, 0, 0, 0);
    STG(aT0, aT1, 0, 1, 0);
    STG(bS0, bS1, 0, 2, 0);
    STG(bT0, bT1, 0, 3, 0);
    STG(bS0, bS1, 1, 2, 1);
    STG(bT0, bT1, 1, 3, 1);
    VMCNT4;
    BAR;

    for (int it = 0; it < 16; ++it) {
        const int kt0 = 2 * it;
        LDA4(0, 0);
        LDB2(0, 0);
        STG(aS0, aS1, 1, 0, kt0 + 1);
        BAR; LGKM0;
        PH_MFMA(0, 0);
        BAR;
        LDB2(0, 2);
        STG(aT0, aT1, 1, 1, kt0 + 1);
        BAR; LGKM0;
        PH_MFMA(0, 2);
        BAR;
        LDA4(0, 64);
        STG(bS0, bS1, 0, 2, kt0 + 2);
        BAR; LGKM0;
        PH_MFMA(4, 2);
        BAR;
        STG(bT0, bT1, 0, 3, kt0 + 2);
        BAR;
        PH_MFMA(4, 0);
        VMCNT4;
        BAR;
        LDA4(1, 0);
        LDB2(1, 0);
        STG(aS0, aS1, 0, 0, kt0 + 2);
        BAR; LGKM0;
        PH_MFMA(0, 0);
        BAR;
        LDB2(1, 2);
        STG(aT0, aT1, 0, 1, kt0 + 2);
        BAR; LGKM0;
        PH_MFMA(0, 2);
        BAR;
        LDA4(1, 64);
        STG(bS0, bS1, 1, 2, kt0 + 3);
        BAR; LGKM0;
        PH_MFMA(4, 2);
        BAR;
        STG(bT0, bT1, 1, 3, kt0 + 3);
        BAR;
        PH_MFMA(4, 0);
        VMCNT4;
        BAR;
    }

    short* Cp = QKV + (long)bx * 1048576;
    const int cbase = wc * 64;
#pragma unroll
    for (int mi = 0; mi < 8; ++mi)
#pragma unroll
        for (int ni = 0; ni < 4; ++ni)
#pragma unroll
            for (int r = 0; r < 4; ++r) {
                const long m = m0 + wr * 128 + mi * 16 + quad * 4 + r;
                Cp[m * 256 + cbase + ni * 16 + l16] = (short)f2bf(acc[mi][ni][r]);
            }

#undef STG
#undef LDA4
#undef LDB2
#undef PH_MFMA
}

// ---------------- RMS-norm + RoPE in-place (Q/K units only) ----------------
__global__ __launch_bounds__(256) void prep_qk(short* __restrict__ QKV,
                                               const float* __restrict__ cosp,
                                               const float* __restrict__ sinp,
                                               const float* __restrict__ qw,
                                               const float* __restrict__ kw) {
    const int t = threadIdx.x, w = t >> 6, lane = t & 63;
    const int d4 = lane * 4;
    const float sgn = (lane < 32) ? -1.0f : 1.0f;
#pragma unroll
    for (int i = 0; i < 4; i++) {
        const int g = blockIdx.x * 16 + w * 4 + i;
        const int u = g >> 12, m = g & 4095;
        short* rowp = QKV + (long)g * 256;
        const short4v raw = *(const short4v*)(rowp + d4);
        float x[4];
#pragma unroll
        for (int j = 0; j < 4; j++) x[j] = bf2f(raw[j]);
        float ss = x[0]*x[0] + x[1]*x[1] + x[2]*x[2] + x[3]*x[3];
#pragma unroll
        for (int msk = 1; msk < 64; msk <<= 1) ss += __shfl_xor(ss, msk, 64);
        const float rinv = rsqrtf(ss * (1.0f / 256.0f) + 1e-6f);
        const float4 wv = *(const float4*)(((u < 16) ? qw : kw) + d4);
        const float wa[4] = {wv.x, wv.y, wv.z, wv.w};
        const float4 cv = *(const float4*)(cosp + (long)m * 256 + d4);
        const float4 sv = *(const float4*)(sinp + (long)m * 256 + d4);
        const float ca[4] = {cv.x, cv.y, cv.z, cv.w};
        const float sa[4] = {sv.x, sv.y, sv.z, sv.w};
        float n[4];
#pragma unroll
        for (int j = 0; j < 4; j++) n[j] = x[j] * rinv * (1.0f + wa[j]);
        const float scale = (u < 16) ? 0.0625f : 1.0f;
        short4v ov;
#pragma unroll
        for (int j = 0; j < 4; j++) {
            const float p = __shfl_xor(n[j], 32, 64);
            ov[j] = (short)f2bf((n[j] * ca[j] + sgn * p * sa[j]) * scale);
        }
        *(short4v*)(rowp + d4) = ov;
    }
}

// ---------------- flash attention (no-max softmax), 2 blocks/CU ----------------
// grid (S/128, NH, B), 512 thr (8 waves). 128-q tile, 64-key kt steps.
// LDS = Kl 32K + Vl 32K + Pl 16K = 81920 B exactly -> 2 blocks/CU (TLP hides
// the per-iteration staging drain; replaces the old K double-buffer).
// Pl: [128][64] with 16B-chunk XOR swizzle (idx ^ (row&7)<<3).
__global__ __launch_bounds__(512, 4) void attn(const short* __restrict__ QKV,
                                               const short* __restrict__ Vt,
                                               short* __restrict__ O) {
    __shared__ __align__(16) short Kl[64 * 256];   // [s][d], chunk-swizzled
    __shared__ __align__(16) short Vl[256 * 64];   // [d][s], chunk-swizzled
    __shared__ __align__(16) short Pl[128 * 64];   // XOR-swizzled; aliased as Ll post-loop
    float* Ll = (float*)Pl;

    const int t = threadIdx.x, w = t >> 6, lane = t & 63;
    const int quad = lane >> 4, l16 = lane & 15;
    const int q0 = blockIdx.x * 128, h = blockIdx.y, b = blockIdx.z;
    const int kh = h >> 1;
    const short* Qp = QKV + ((long)h * 4096 + b * 2048 + q0) * 256;
    const short* Kp = QKV + ((long)(16 + kh) * 4096 + b * 2048) * 256;
    const short* Vp = Vt + (long)(kh * 2 + b) * 256 * 2048;

    short8 qf[8];
#pragma unroll
    for (int ks = 0; ks < 8; ks++)
        qf[ks] = *(const short8*)(Qp + (w * 16 + l16) * 256 + ks * 32 + quad * 8);

    f32x4 acc[4][4] = {};
    float li_[4] = {0.0f, 0.0f, 0.0f, 0.0f};

    const int qh = w >> 2, dstr = (w & 3) * 64;

    for (int kt = 0; kt < 32; kt++) {
        const int k0 = kt * 64;
        // ---- stage V(kt), K(kt); prior-iter barrier (c) guarantees overwrite safety
#pragma unroll
        for (int i = 0; i < 4; i++) {
            const int c = i * 512 + t;
            const int dV = c >> 3, j = c & 7;
            GLOAD16(Vp + (long)dV * 2048 + k0 + (j ^ (dV & 7)) * 8, Vl + c * 8);
        }
#pragma unroll
        for (int i = 0; i < 4; i++) {
            const int c = i * 512 + t;
            const int rK = c >> 5, j = c & 31;
            GLOAD16(Kp + (long)(k0 + rK) * 256 + (j ^ (rK & 31)) * 8, Kl + c * 8);
        }
        __syncthreads();   // (a) vmcnt(0)+bar: K(kt), V(kt) visible to all waves

        // ---- S = Q K^T ----
        f32x4 sc[4] = {};
        __builtin_amdgcn_s_setprio(1);
#pragma unroll
        for (int ct = 0; ct < 4; ct++) {
            const int rowK = ct * 16 + l16;
#pragma unroll
            for (int ks = 0; ks < 8; ks++) {
                const int dc = (ks * 4 + quad) ^ (rowK & 31);
                const short8 kf = *(const short8*)(Kl + rowK * 256 + dc * 8);
                sc[ct] = __builtin_amdgcn_mfma_f32_16x16x32_bf16(qf[ks], kf, sc[ct], 0, 0, 0);
            }
        }
        __builtin_amdgcn_s_setprio(0);

        // ---- P = exp(S) (no max; |S|<=16), per-lane l partials, swizzled P write ----
#pragma unroll
        for (int ct = 0; ct < 4; ct++) {
#pragma unroll
            for (int r = 0; r < 4; r++) {
                const float p = __expf(sc[ct][r]);
                li_[r] += p;
                const int prow = w * 16 + quad * 4 + r;
                Pl[prow * 64 + ((ct * 16 + l16) ^ ((prow & 7) << 3))] = (short)f2bf(p);
            }
        }
        __syncthreads();   // (b) P visible

        // ---- O += P V (wave w: q-half qh, d-strip dstr) ----
        __builtin_amdgcn_s_setprio(1);
#pragma unroll
        for (int k2 = 0; k2 < 2; k2++) {
            short8 pf[4];
#pragma unroll
            for (int mi2 = 0; mi2 < 4; mi2++) {
                const int prow = qh * 64 + mi2 * 16 + l16;
                pf[mi2] = *(const short8*)(Pl + prow * 64 + ((k2 * 32 + quad * 8) ^ ((prow & 7) << 3)));
            }
#pragma unroll
            for (int ni = 0; ni < 4; ni++) {
                const int dV = dstr + ni * 16 + l16;
                const int dc = (k2 * 4 + quad) ^ (dV & 7);
                const short8 vf = *(const short8*)(Vl + dV * 64 + dc * 8);
#pragma unroll
                for (int mi2 = 0; mi2 < 4; mi2++)
                    acc[mi2][ni] = __builtin_amdgcn_mfma_f32_16x16x32_bf16(pf[mi2], vf, acc[mi2][ni], 0, 0, 0);
            }
        }
        __builtin_amdgcn_s_setprio(0);
        __syncthreads();   // (c) all PV reads done -> Kl/Vl/Pl overwritable
    }

    // epilogue: reduce l across 16 column-lanes; Ll aliases Pl (safe after (c))
#pragma unroll
    for (int r = 0; r < 4; r++) {
        float v = li_[r];
        v += __shfl_xor(v, 1, 64);
        v += __shfl_xor(v, 2, 64);
        v += __shfl_xor(v, 4, 64);
        v += __shfl_xor(v, 8, 64);
        if (l16 == 0) Ll[w * 16 + quad * 4 + r] = v;
    }
    __syncthreads();

    short* Op = O + (long)(b * 2048 + q0 + qh * 64) * 4096 + h * 256 + dstr;
#pragma unroll
    for (int mi2 = 0; mi2 < 4; mi2++) {
        const float4 lv = *(const float4*)(Ll + qh * 64 + mi2 * 16 + quad * 4);
        const float inv[4] = {1.0f / lv.x, 1.0f / lv.y, 1.0f / lv.z, 1.0f / lv.w};
#pragma unroll
        for (int ni = 0; ni < 4; ni++)
#pragma unroll
            for (int r = 0; r < 4; r++)
                Op[(long)(mi2 * 16 + quad * 4 + r) * 4096 + ni * 16 + l16] =
                    (short)f2bf(acc[mi2][ni][r] * inv[r]);
    }
}

// ---------------- launch ----------------
extern "C" void kernel_launch(void* const* d_in, const int* in_sizes, int n_in,
                              void* d_out, int out_size, void* d_ws, size_t ws_size,
                              hipStream_t stream) {
    const float* hs   = (const float*)d_in[0];
    const float* cosp = (const float*)d_in[1];
    const float* sinp = (const float*)d_in[2];
    const float* wqkv = (const float*)d_in[3];
    const float* wo   = (const float*)d_in[4];
    const float* qnw  = (const float*)d_in[5];
    const float* knw  = (const float*)d_in[6];
    float* out = (float*)d_out;

    short* poolA  = (short*)d_ws;
    short* Xb     = poolA;                                  // [4096][2048]
    short* Wqkv_t = poolA + (size_t)4096 * 2048;            // [8192][2048]
    short* QKV    = poolA + (size_t)4096 * 2048 + (size_t)8192 * 2048; // [32][4096][256]
    short* Vt     = poolA;                                  // [16][256][2048] (over Xb)
    short* Ob     = poolA + (size_t)16 * 256 * 2048;        // [4096][4096] (over Wqkv_t)
    short* Wo_t   = QKV;                                    // [2048][4096] (over QKV, post-attn)

    cvt_f32_bf16<<<8192, 256, 0, stream>>>(hs, Xb);
    transpose_cvt<<<dim3(128, 32), 256, 0, stream>>>(wqkv, Wqkv_t, 2048, 8192);
    gemm256_qkv<<<dim3(32, 16), 512, 0, stream>>>(Xb, Wqkv_t, QKV);
    prep_qk<<<6144, 256, 0, stream>>>(QKV, cosp, sinp, qnw, knw);
    vtrans<<<dim3(32, 4, 16), 256, 0, stream>>>(QKV, Vt);
    attn<<<dim3(16, 16, 2), 512, 0, stream>>>(QKV, Vt, Ob);
    transpose_cvt<<<dim3(32, 64), 256, 0, stream>>>(wo, Wo_t, 4096, 2048);
    gemm_nt<2048, 4096, 0><<<dim3(16, 32), 256, 0, stream>>>(Ob, Wo_t, (void*)out);
}

// Round 6
// 579.148 us; speedup vs baseline: 1.8023x; 1.8023x over previous
//
#include <hip/hip_runtime.h>
#include <stdint.h>

// ---------------- types & helpers ----------------
typedef __attribute__((ext_vector_type(8))) short short8;
typedef __attribute__((ext_vector_type(4))) short short4v;
typedef __attribute__((ext_vector_type(4))) float f32x4;

#define GLOAD16(gp, lp) __builtin_amdgcn_global_load_lds( \
    (__attribute__((address_space(1))) void*)(gp),        \
    (__attribute__((address_space(3))) void*)(lp), 16, 0, 0)

#define BAR   __builtin_amdgcn_s_barrier()
#define LGKM0 asm volatile("s_waitcnt lgkmcnt(0)" ::: "memory")
#define VMCNT4 asm volatile("s_waitcnt vmcnt(4)" ::: "memory")

__device__ __forceinline__ unsigned short f2bf(float f) {
    union { float f; unsigned u; } v; v.f = f;
    unsigned u = v.u + 0x7fffu + ((v.u >> 16) & 1u);
    return (unsigned short)(u >> 16);
}
__device__ __forceinline__ float bf2f(short s) {
    union { unsigned u; float f; } v;
    v.u = ((unsigned)(unsigned short)s) << 16;
    return v.f;
}

// ---------------- fp32 -> bf16 convert ----------------
__global__ __launch_bounds__(256) void cvt_f32_bf16(const float* __restrict__ in,
                                                    short* __restrict__ out) {
    const int i = (blockIdx.x * 256 + threadIdx.x) * 4;
    const float4 v = *(const float4*)(in + i);
    short4v o;
    o[0] = (short)f2bf(v.x); o[1] = (short)f2bf(v.y);
    o[2] = (short)f2bf(v.z); o[3] = (short)f2bf(v.w);
    *(short4v*)(out + i) = o;
}

// ---------------- fp32 [R][C] -> bf16 [C][R] transpose+convert ----------------
__global__ __launch_bounds__(256) void transpose_cvt(const float* __restrict__ in,
                                                     short* __restrict__ out,
                                                     int R, int C) {
    __shared__ float tile[64 * 65];
    const int t = threadIdx.x;
    const int r0 = blockIdx.y * 64, c0 = blockIdx.x * 64;
    const int rl = t >> 4, cl4 = (t & 15) * 4;
#pragma unroll
    for (int rep = 0; rep < 4; rep++) {
        const int r = rep * 16 + rl;
        const float4 v = *(const float4*)(in + (long)(r0 + r) * C + c0 + cl4);
        tile[r * 65 + cl4 + 0] = v.x;
        tile[r * 65 + cl4 + 1] = v.y;
        tile[r * 65 + cl4 + 2] = v.z;
        tile[r * 65 + cl4 + 3] = v.w;
    }
    __syncthreads();
#pragma unroll
    for (int rep = 0; rep < 4; rep++) {
        const int cc = rep * 16 + rl;
        short4v o;
#pragma unroll
        for (int j = 0; j < 4; j++) o[j] = (short)f2bf(tile[(cl4 + j) * 65 + cc]);
        *(short4v*)(out + (long)(c0 + cc) * R + r0 + cl4) = o;
    }
}

// ---------------- bf16 V transpose ----------------
__global__ __launch_bounds__(256) void vtrans(const short* __restrict__ QKV,
                                              short* __restrict__ Vt) {
    __shared__ short tile[64 * 72];
    const int t = threadIdx.x;
    const int s0 = blockIdx.x * 64, d0 = blockIdx.y * 64;
    const int hb = blockIdx.z >> 1, b = blockIdx.z & 1;
    const short* src = QKV + ((long)(24 + hb) * 4096 + b * 2048) * 256;
    short* dst = Vt + (long)blockIdx.z * 256 * 2048;
#pragma unroll
    for (int p = 0; p < 2; p++) {
        const int c = p * 256 + t;
        const int r = c >> 3, col8 = (c & 7) * 8;
        *(short8*)(tile + r * 72 + col8) = *(const short8*)(src + (long)(s0 + r) * 256 + d0 + col8);
    }
    __syncthreads();
#pragma unroll
    for (int p = 0; p < 2; p++) {
        const int c = p * 256 + t;
        const int dr = c >> 3, sc8 = (c & 7) * 8;
        short8 o;
#pragma unroll
        for (int j = 0; j < 8; j++) o[j] = tile[(sc8 + j) * 72 + dr];
        *(short8*)(dst + (long)(d0 + dr) * 2048 + s0 + sc8) = o;
    }
}

// ---------------- NT GEMM (128x128 m97-structure; kept for o-proj) ----------------
template<int N, int K, int OUTMODE>
__global__ __launch_bounds__(256) void gemm_nt(const short* __restrict__ A,
                                               const short* __restrict__ Bt,
                                               void* __restrict__ Cv) {
    __shared__ __align__(16) short Al[128 * 32];
    __shared__ __align__(16) short Bl[128 * 32];
    const int t = threadIdx.x;
    const int lane = t & 63, w = t >> 6;
    const int quad = lane >> 4, l16 = lane & 15;
    const int wr = w >> 1, wc = w & 1;
    const long m0 = (long)blockIdx.y * 128, n0 = (long)blockIdx.x * 128;

    const short* Ag0 = A + (m0 + (t >> 2)) * K + (t & 3) * 8;
    const short* Bg0 = Bt + (n0 + (t >> 2)) * K + (t & 3) * 8;

    f32x4 acc[4][4] = {};

    for (int k0 = 0; k0 < K; k0 += 32) {
        __syncthreads();
        GLOAD16(Ag0 + k0,            Al + t * 8);
        GLOAD16(Ag0 + 64 * K + k0,   Al + (t + 256) * 8);
        GLOAD16(Bg0 + k0,            Bl + t * 8);
        GLOAD16(Bg0 + 64 * K + k0,   Bl + (t + 256) * 8);
        __syncthreads();
        short8 af[4], bfr[4];
#pragma unroll
        for (int i = 0; i < 4; i++)
            af[i] = *(const short8*)(Al + (wr * 64 + i * 16 + l16) * 32 + quad * 8);
#pragma unroll
        for (int i = 0; i < 4; i++)
            bfr[i] = *(const short8*)(Bl + (wc * 64 + i * 16 + l16) * 32 + quad * 8);
#pragma unroll
        for (int mi = 0; mi < 4; mi++)
#pragma unroll
            for (int ni = 0; ni < 4; ni++)
                acc[mi][ni] = __builtin_amdgcn_mfma_f32_16x16x32_bf16(af[mi], bfr[ni], acc[mi][ni], 0, 0, 0);
    }

    const long crow = m0 + wr * 64 + quad * 4;
    const long ccol = n0 + wc * 64 + l16;
    if constexpr (OUTMODE == 0) {
        float* C = (float*)Cv;
#pragma unroll
        for (int mi = 0; mi < 4; mi++)
#pragma unroll
            for (int ni = 0; ni < 4; ni++)
#pragma unroll
                for (int r = 0; r < 4; r++)
                    C[(crow + mi * 16 + r) * N + ccol + ni * 16] = acc[mi][ni][r];
    } else {
        short* C = (short*)Cv;
#pragma unroll
        for (int mi = 0; mi < 4; mi++)
#pragma unroll
            for (int ni = 0; ni < 4; ni++)
#pragma unroll
                for (int r = 0; r < 4; r++) {
                    const long m = crow + mi * 16 + r;
                    const long f = ccol + ni * 16;
                    C[(f >> 8) * 1048576 + m * 256 + (f & 255)] = (short)f2bf(acc[mi][ni][r]);
                }
    }
}

// ---------------- 256x256 8-phase NT GEMM -> QKV scatter (T1+T2+T3/T4+T5) ----------------
__global__ __launch_bounds__(512, 2) void gemm256_qkv(const short* __restrict__ A,
                                                      const short* __restrict__ Bt,
                                                      short* __restrict__ QKV) {
    constexpr int K = 2048;
    constexpr int NTM = 31;                       // (K/64) - 1, pow2 wrap for tail stages
    __shared__ __align__(16) short L[2][4][8192]; // [buf][A0,A1,B0,B1][128*64]

    const int t = threadIdx.x;
    const int lane = t & 63, w = t >> 6;
    const int quad = lane >> 4, l16 = lane & 15;
    const int wr = w >> 2, wc = w & 3;
    const int bh = 2 + (wc >> 1);        // this wave's B half-slot
    const int brow0 = (wc & 1) * 64;     // B in-half row base

    // T1: bijective XCD swizzle (nwg = 512, 512 % 8 == 0)
    const int flat = blockIdx.y * 32 + blockIdx.x;
    const int swz = (flat & 7) * 64 + (flat >> 3);
    const int bx = swz & 31, by = swz >> 5;
    const long m0 = (long)by * 256, n0 = (long)bx * 256;

    // staging sources: linear LDS dest, inverse-st_16x32 pre-swizzled global k
    const int r0 = t >> 3, r1 = (512 + t) >> 3;
    const int k0s = ((t & 7) * 8) ^ (((r0 >> 2) & 1) << 4);
    const int k1s = ((t & 7) * 8) ^ (((r1 >> 2) & 1) << 4);
    const short* aS0 = A + (m0 + r0) * K + k0s;
    const short* aS1 = A + (m0 + r1) * K + k1s;
    const short* aT0 = aS0 + 128 * K;
    const short* aT1 = aS1 + 128 * K;
    const short* bS0 = Bt + (n0 + r0) * K + k0s;
    const short* bS1 = Bt + (n0 + r1) * K + k1s;
    const short* bT0 = bS0 + 128 * K;
    const short* bT1 = bS1 + 128 * K;

#define STG(p0, p1, bsel, slot, kt) do {                     \
    const int _ko = ((kt) & NTM) * 64;                       \
    GLOAD16((p0) + _ko, &L[bsel][slot][t * 8]);              \
    GLOAD16((p1) + _ko, &L[bsel][slot][4096 + t * 8]);       \
} while (0)

#define LDA4(bsel, rb) do {                                                        \
    _Pragma("unroll") for (int m = 0; m < 4; ++m) {                                \
        const int _r = (rb) + m * 16 + l16;                                        \
        const int _sw = ((_r >> 2) & 1) << 4;                                      \
        a[m][0] = *(const short8*)(&L[bsel][wr][_r * 64 + ((quad * 8) ^ _sw)]);    \
        a[m][1] = *(const short8*)(&L[bsel][wr][_r * 64 + ((32 + quad * 8) ^ _sw)]); \
    } } while (0)

#define LDB2(bsel, nb) do {                                                        \
    _Pragma("unroll") for (int n = 0; n < 2; ++n) {                                \
        const int _r = brow0 + ((nb) + n) * 16 + l16;                              \
        const int _sw = ((_r >> 2) & 1) << 4;                                      \
        b[(nb) + n][0] = *(const short8*)(&L[bsel][bh][_r * 64 + ((quad * 8) ^ _sw)]); \
        b[(nb) + n][1] = *(const short8*)(&L[bsel][bh][_r * 64 + ((32 + quad * 8) ^ _sw)]); \
    } } while (0)

#define PH_MFMA(MB, NB)                                                            \
    __builtin_amdgcn_s_setprio(1);                                                 \
    _Pragma("unroll") for (int m = 0; m < 4; ++m)                                  \
    _Pragma("unroll") for (int n = 0; n < 2; ++n)                                  \
    _Pragma("unroll") for (int kk = 0; kk < 2; ++kk)                               \
        acc[(MB) + m][(NB) + n] = __builtin_amdgcn_mfma_f32_16x16x32_bf16(         \
            a[m][kk], b[(NB) + n][kk], acc[(MB) + m][(NB) + n], 0, 0, 0);          \
    __builtin_amdgcn_s_setprio(0);

    short8 a[4][2], b[4][2];
    f32x4 acc[8][4] = {};

    STG(aS0, aS1, 0, 0, 0);
    STG(aT0, aT1, 0, 1, 0);
    STG(bS0, bS1, 0, 2, 0);
    STG(bT0, bT1, 0, 3, 0);
    STG(bS0, bS1, 1, 2, 1);
    STG(bT0, bT1, 1, 3, 1);
    VMCNT4;
    BAR;

    for (int it = 0; it < 16; ++it) {
        const int kt0 = 2 * it;
        LDA4(0, 0);
        LDB2(0, 0);
        STG(aS0, aS1, 1, 0, kt0 + 1);
        BAR; LGKM0;
        PH_MFMA(0, 0);
        BAR;
        LDB2(0, 2);
        STG(aT0, aT1, 1, 1, kt0 + 1);
        BAR; LGKM0;
        PH_MFMA(0, 2);
        BAR;
        LDA4(0, 64);
        STG(bS0, bS1, 0, 2, kt0 + 2);
        BAR; LGKM0;
        PH_MFMA(4, 2);
        BAR;
        STG(bT0, bT1, 0, 3, kt0 + 2);
        BAR;
        PH_MFMA(4, 0);
        VMCNT4;
        BAR;
        LDA4(1, 0);
        LDB2(1, 0);
        STG(aS0, aS1, 0, 0, kt0 + 2);
        BAR; LGKM0;
        PH_MFMA(0, 0);
        BAR;
        LDB2(1, 2);
        STG(aT0, aT1, 0, 1, kt0 + 2);
        BAR; LGKM0;
        PH_MFMA(0, 2);
        BAR;
        LDA4(1, 64);
        STG(bS0, bS1, 1, 2, kt0 + 3);
        BAR; LGKM0;
        PH_MFMA(4, 2);
        BAR;
        STG(bT0, bT1, 1, 3, kt0 + 3);
        BAR;
        PH_MFMA(4, 0);
        VMCNT4;
        BAR;
    }

    short* Cp = QKV + (long)bx * 1048576;
    const int cbase = wc * 64;
#pragma unroll
    for (int mi = 0; mi < 8; ++mi)
#pragma unroll
        for (int ni = 0; ni < 4; ++ni)
#pragma unroll
            for (int r = 0; r < 4; ++r) {
                const long m = m0 + wr * 128 + mi * 16 + quad * 4 + r;
                Cp[m * 256 + cbase + ni * 16 + l16] = (short)f2bf(acc[mi][ni][r]);
            }

#undef STG
#undef LDA4
#undef LDB2
#undef PH_MFMA
}

// ---------------- RMS-norm + RoPE in-place (Q/K units only) ----------------
__global__ __launch_bounds__(256) void prep_qk(short* __restrict__ QKV,
                                               const float* __restrict__ cosp,
                                               const float* __restrict__ sinp,
                                               const float* __restrict__ qw,
                                               const float* __restrict__ kw) {
    const int t = threadIdx.x, w = t >> 6, lane = t & 63;
    const int d4 = lane * 4;
    const float sgn = (lane < 32) ? -1.0f : 1.0f;
#pragma unroll
    for (int i = 0; i < 4; i++) {
        const int g = blockIdx.x * 16 + w * 4 + i;
        const int u = g >> 12, m = g & 4095;
        short* rowp = QKV + (long)g * 256;
        const short4v raw = *(const short4v*)(rowp + d4);
        float x[4];
#pragma unroll
        for (int j = 0; j < 4; j++) x[j] = bf2f(raw[j]);
        float ss = x[0]*x[0] + x[1]*x[1] + x[2]*x[2] + x[3]*x[3];
#pragma unroll
        for (int msk = 1; msk < 64; msk <<= 1) ss += __shfl_xor(ss, msk, 64);
        const float rinv = rsqrtf(ss * (1.0f / 256.0f) + 1e-6f);
        const float4 wv = *(const float4*)(((u < 16) ? qw : kw) + d4);
        const float wa[4] = {wv.x, wv.y, wv.z, wv.w};
        const float4 cv = *(const float4*)(cosp + (long)m * 256 + d4);
        const float4 sv = *(const float4*)(sinp + (long)m * 256 + d4);
        const float ca[4] = {cv.x, cv.y, cv.z, cv.w};
        const float sa[4] = {sv.x, sv.y, sv.z, sv.w};
        float n[4];
#pragma unroll
        for (int j = 0; j < 4; j++) n[j] = x[j] * rinv * (1.0f + wa[j]);
        const float scale = (u < 16) ? 0.0625f : 1.0f;
        short4v ov;
#pragma unroll
        for (int j = 0; j < 4; j++) {
            const float p = __shfl_xor(n[j], 32, 64);
            ov[j] = (short)f2bf((n[j] * ca[j] + sgn * p * sa[j]) * scale);
        }
        *(short4v*)(rowp + d4) = ov;
    }
}

// ---------------- flash attention (no-max softmax), 1 block/CU, K dbuf ----------------
// grid (S/128, NH, B), 512 thr (8 waves). 128-q tile, 64-key kt steps.
// R3 change vs R1 base: S-phase wave partition is 32 q-rows x 32 keys per wave
// (was 16 q x 64 keys) -> each K-fragment LDS read reused across 2 q-subtiles,
// halving S-phase LDS traffic (256->128 KB/blk/kt). Q-frags double to 64 VGPR
// (fine at 1 blk/CU). Row-sums now split across wave pairs -> 2-step Ll combine.
// PV phase, staging, swizzles unchanged (HW-verified). Pl is 64-stride + XOR
// swizzle (0 bank conflicts measured in R2).
__global__ __launch_bounds__(512, 2) void attn(const short* __restrict__ QKV,
                                               const short* __restrict__ Vt,
                                               short* __restrict__ O) {
    __shared__ __align__(16) short Kl[2][64 * 256];  // [s][d], chunk-swizzled, dbuf
    __shared__ __align__(16) short Vl[256 * 64];     // [d][s], chunk-swizzled
    __shared__ __align__(16) short Pl[128 * 64];     // XOR-swizzled rows
    __shared__ __align__(16) float Ll[128];

    const int t = threadIdx.x, w = t >> 6, lane = t & 63;
    const int quad = lane >> 4, l16 = lane & 15;
    const int q0 = blockIdx.x * 128, h = blockIdx.y, b = blockIdx.z;
    const int kh = h >> 1;
    const short* Qp = QKV + ((long)h * 4096 + b * 2048 + q0) * 256;
    const short* Kp = QKV + ((long)(16 + kh) * 4096 + b * 2048) * 256;
    const short* Vp = Vt + (long)(kh * 2 + b) * 256 * 2048;

    // S-phase: wave w owns q rows [32*(w>>1), +32) x keys [32*(w&1), +32)
    const int qh2 = w >> 1, kh2 = w & 1;
    short8 qf2[2][8];
#pragma unroll
    for (int mi = 0; mi < 2; mi++)
#pragma unroll
        for (int ks = 0; ks < 8; ks++)
            qf2[mi][ks] = *(const short8*)(Qp + (qh2 * 32 + mi * 16 + l16) * 256 + ks * 32 + quad * 8);

    f32x4 acc[4][4] = {};
    float li_[2][4] = {};

    // PV-phase ownership (independent of S split): q-half (w>>2), d-strip (w&3)*64
    const int qh = w >> 2, dstr = (w & 3) * 64;

    // prologue: stage K tile 0 into Kl[0]
#pragma unroll
    for (int i = 0; i < 4; i++) {
        const int c = i * 512 + t;
        const int rK = c >> 5, j = c & 31;
        GLOAD16(Kp + (long)rK * 256 + (j ^ (rK & 31)) * 8, Kl[0] + c * 8);
    }

    for (int kt = 0; kt < 32; kt++) {
        const int k0 = kt * 64;
        __syncthreads();   // (a) prev PV done (Vl/Pl free); K(kt) landed in Kl[kt&1]

        // issue V(kt) and K(kt+1) — land by (b), hidden under S+softmax
#pragma unroll
        for (int i = 0; i < 4; i++) {
            const int c = i * 512 + t;
            const int dV = c >> 3, j = c & 7;
            GLOAD16(Vp + (long)dV * 2048 + k0 + (j ^ (dV & 7)) * 8, Vl + c * 8);
        }
        const int kn = ((kt + 1) & 31) * 64;   // wrap: last iter reloads tile 0 (unused)
#pragma unroll
        for (int i = 0; i < 4; i++) {
            const int c = i * 512 + t;
            const int rK = c >> 5, j = c & 31;
            GLOAD16(Kp + (long)(kn + rK) * 256 + (j ^ (rK & 31)) * 8, Kl[(kt + 1) & 1] + c * 8);
        }

        // ---- S = Q K^T on Kl[kt&1]: 2 q-subtiles x 2 k-subtiles, K-frag reused ----
        const short* Kb = Kl[kt & 1];
        f32x4 sc[2][2] = {};
        __builtin_amdgcn_s_setprio(1);
#pragma unroll
        for (int ct2 = 0; ct2 < 2; ct2++) {
            const int rowK = kh2 * 32 + ct2 * 16 + l16;
#pragma unroll
            for (int ks = 0; ks < 8; ks++) {
                const int dc = (ks * 4 + quad) ^ (rowK & 31);
                const short8 kf = *(const short8*)(Kb + rowK * 256 + dc * 8);
                sc[0][ct2] = __builtin_amdgcn_mfma_f32_16x16x32_bf16(qf2[0][ks], kf, sc[0][ct2], 0, 0, 0);
                sc[1][ct2] = __builtin_amdgcn_mfma_f32_16x16x32_bf16(qf2[1][ks], kf, sc[1][ct2], 0, 0, 0);
            }
        }
        __builtin_amdgcn_s_setprio(0);

        // ---- P = exp(S) (no max; |S|<=16), per-lane l partials, swizzled P write ----
#pragma unroll
        for (int mi = 0; mi < 2; mi++)
#pragma unroll
            for (int ct2 = 0; ct2 < 2; ct2++)
#pragma unroll
                for (int r = 0; r < 4; r++) {
                    const float p = __expf(sc[mi][ct2][r]);
                    li_[mi][r] += p;
                    const int prow = qh2 * 32 + mi * 16 + quad * 4 + r;
                    const int pcol = kh2 * 32 + ct2 * 16 + l16;
                    Pl[prow * 64 + (pcol ^ ((prow & 7) << 3))] = (short)f2bf(p);
                }
        __syncthreads();   // (b) V(kt) & K(kt+1) landed; P visible

        // ---- O += P V (wave w: q-half qh, d-strip dstr) ----
        __builtin_amdgcn_s_setprio(1);
#pragma unroll
        for (int k2 = 0; k2 < 2; k2++) {
            short8 pf[4];
#pragma unroll
            for (int mi2 = 0; mi2 < 4; mi2++) {
                const int prow = qh * 64 + mi2 * 16 + l16;
                pf[mi2] = *(const short8*)(Pl + prow * 64 + ((k2 * 32 + quad * 8) ^ ((prow & 7) << 3)));
            }
#pragma unroll
            for (int ni = 0; ni < 4; ni++) {
                const int dV = dstr + ni * 16 + l16;
                const int dc = (k2 * 4 + quad) ^ (dV & 7);
                const short8 vf = *(const short8*)(Vl + dV * 64 + dc * 8);
#pragma unroll
                for (int mi2 = 0; mi2 < 4; mi2++)
                    acc[mi2][ni] = __builtin_amdgcn_mfma_f32_16x16x32_bf16(pf[mi2], vf, acc[mi2][ni], 0, 0, 0);
            }
        }
        __builtin_amdgcn_s_setprio(0);
    }

    // epilogue: wave-reduce l over 16 column-lanes, then combine across wave pairs
    float lv_[2][4];
#pragma unroll
    for (int mi = 0; mi < 2; mi++)
#pragma unroll
        for (int r = 0; r < 4; r++) {
            float v = li_[mi][r];
            v += __shfl_xor(v, 1, 64);
            v += __shfl_xor(v, 2, 64);
            v += __shfl_xor(v, 4, 64);
            v += __shfl_xor(v, 8, 64);
            lv_[mi][r] = v;
        }
    __syncthreads();   // all PV reads done; Ll write phase begins
    if (kh2 == 0 && l16 == 0) {
#pragma unroll
        for (int mi = 0; mi < 2; mi++)
#pragma unroll
            for (int r = 0; r < 4; r++)
                Ll[qh2 * 32 + mi * 16 + quad * 4 + r] = lv_[mi][r];
    }
    __syncthreads();
    if (kh2 == 1 && l16 == 0) {
#pragma unroll
        for (int mi = 0; mi < 2; mi++)
#pragma unroll
            for (int r = 0; r < 4; r++)
                Ll[qh2 * 32 + mi * 16 + quad * 4 + r] += lv_[mi][r];
    }
    __syncthreads();

    short* Op = O + (long)(b * 2048 + q0 + qh * 64) * 4096 + h * 256 + dstr;
#pragma unroll
    for (int mi2 = 0; mi2 < 4; mi2++) {
        const float4 lv = *(const float4*)(Ll + qh * 64 + mi2 * 16 + quad * 4);
        const float inv[4] = {1.0f / lv.x, 1.0f / lv.y, 1.0f / lv.z, 1.0f / lv.w};
#pragma unroll
        for (int ni = 0; ni < 4; ni++)
#pragma unroll
            for (int r = 0; r < 4; r++)
                Op[(long)(mi2 * 16 + quad * 4 + r) * 4096 + ni * 16 + l16] =
                    (short)f2bf(acc[mi2][ni][r] * inv[r]);
    }
}

// ---------------- launch ----------------
extern "C" void kernel_launch(void* const* d_in, const int* in_sizes, int n_in,
                              void* d_out, int out_size, void* d_ws, size_t ws_size,
                              hipStream_t stream) {
    const float* hs   = (const float*)d_in[0];
    const float* cosp = (const float*)d_in[1];
    const float* sinp = (const float*)d_in[2];
    const float* wqkv = (const float*)d_in[3];
    const float* wo   = (const float*)d_in[4];
    const float* qnw  = (const float*)d_in[5];
    const float* knw  = (const float*)d_in[6];
    float* out = (float*)d_out;

    short* poolA  = (short*)d_ws;
    short* Xb     = poolA;                                  // [4096][2048]
    short* Wqkv_t = poolA + (size_t)4096 * 2048;            // [8192][2048]
    short* QKV    = poolA + (size_t)4096 * 2048 + (size_t)8192 * 2048; // [32][4096][256]
    short* Vt     = poolA;                                  // [16][256][2048] (over Xb)
    short* Ob     = poolA + (size_t)16 * 256 * 2048;        // [4096][4096] (over Wqkv_t)
    short* Wo_t   = QKV;                                    // [2048][4096] (over QKV, post-attn)

    cvt_f32_bf16<<<8192, 256, 0, stream>>>(hs, Xb);
    transpose_cvt<<<dim3(128, 32), 256, 0, stream>>>(wqkv, Wqkv_t, 2048, 8192);
    gemm256_qkv<<<dim3(32, 16), 512, 0, stream>>>(Xb, Wqkv_t, QKV);
    prep_qk<<<6144, 256, 0, stream>>>(QKV, cosp, sinp, qnw, knw);
    vtrans<<<dim3(32, 4, 16), 256, 0, stream>>>(QKV, Vt);
    attn<<<dim3(16, 16, 2), 512, 0, stream>>>(QKV, Vt, Ob);
    transpose_cvt<<<dim3(32, 64), 256, 0, stream>>>(wo, Wo_t, 4096, 2048);
    gemm_nt<2048, 4096, 0><<<dim3(16, 32), 256, 0, stream>>>(Ob, Wo_t, (void*)out);
}